// Round 1
// baseline (204.927 us; speedup 1.0000x reference)
//
#include <hip/hip_runtime.h>

// dcn_56925496541545: 3 iterations of (3x3 neighbor-avg stencil -> convex
// combo with (w1, 1-w1) -> sigmoid) on 4M flattened 3x3 patches; output is
// element 0 of each patch after iteration 3.
//
// Dependency-cone pruning: final out = x3[0] needs x2[{0,1,3,4}], which needs
// all 9 of x1. So: iter1 = 9 sigmoids, iter2 = 4, iter3 = 1 (14 vs naive 27).
//
// Memory plan: block of 256 threads stages 256 patches (2304 floats) via 576
// coalesced float4 loads into LDS; per-thread LDS reads at stride 9 (odd ->
// max 2 lanes/bank, free); one coalesced float store per patch.

__device__ __forceinline__ float sigmoid_fast(float z) {
    // 1/(1+exp(-z)) = 1/(1 + 2^(-z*log2(e))), via v_exp_f32 + v_rcp_f32.
    float e = __builtin_amdgcn_exp2f(z * -1.44269504088896340736f);
    return __builtin_amdgcn_rcpf(1.0f + e);
}

#define PPB 256  // patches per block (== blockDim.x)

__global__ __launch_bounds__(256) void dcn_56925496541545_kernel(
    const float* __restrict__ x, const float* __restrict__ w1p,
    float* __restrict__ out, int n)
{
    __shared__ float lds[PPB * 9];

    const int base = blockIdx.x * PPB;
    const int npatch = min(PPB, n - base);
    const int nfloat = npatch * 9;
    const float* src = x + (size_t)base * 9;

    // Staged coalesced load: base*9 = blockIdx*2304 floats -> 16B aligned.
    const int nv4 = nfloat >> 2;
    const float4* src4 = (const float4*)src;
    for (int i = threadIdx.x; i < nv4; i += blockDim.x) {
        float4 v = src4[i];
        float* d = &lds[i << 2];
        d[0] = v.x; d[1] = v.y; d[2] = v.z; d[3] = v.w;
    }
    for (int i = (nv4 << 2) + threadIdx.x; i < nfloat; i += blockDim.x)
        lds[i] = src[i];
    __syncthreads();

    const int t = threadIdx.x;
    if (t >= npatch) return;

    const float w1 = *w1p;
    const float w2 = 1.0f - w1;
    const float i3 = (1.0f / 3.0f), i5 = 0.2f, i8 = 0.125f;

    float a[9];
#pragma unroll
    for (int k = 0; k < 9; ++k) a[k] = lds[t * 9 + k];

    // ---- iteration 1: all 9 positions ----
    float b[9];
    b[0] = (a[1] + a[3] + a[4]) * i3;
    b[1] = (a[0] + a[2] + a[3] + a[4] + a[5]) * i5;
    b[2] = (a[1] + a[4] + a[5]) * i3;
    b[3] = (a[0] + a[1] + a[4] + a[6] + a[7]) * i5;
    b[4] = (a[0] + a[1] + a[2] + a[3] + a[5] + a[6] + a[7] + a[8]) * i8;
    b[5] = (a[1] + a[2] + a[4] + a[7] + a[8]) * i5;
    b[6] = (a[3] + a[4] + a[7]) * i3;
    b[7] = (a[3] + a[4] + a[5] + a[6] + a[8]) * i5;
    b[8] = (a[4] + a[5] + a[7]) * i3;

    float y[9];
#pragma unroll
    for (int k = 0; k < 9; ++k) y[k] = sigmoid_fast(w1 * a[k] + w2 * b[k]);

    // ---- iteration 2: only positions {0,1,3,4} feed the final output ----
    float c0 = (y[1] + y[3] + y[4]) * i3;
    float c1 = (y[0] + y[2] + y[3] + y[4] + y[5]) * i5;
    float c3 = (y[0] + y[1] + y[4] + y[6] + y[7]) * i5;
    float c4 = (y[0] + y[1] + y[2] + y[3] + y[5] + y[6] + y[7] + y[8]) * i8;

    float z0 = sigmoid_fast(w1 * y[0] + w2 * c0);
    float z1 = sigmoid_fast(w1 * y[1] + w2 * c1);
    float z3 = sigmoid_fast(w1 * y[3] + w2 * c3);
    float z4 = sigmoid_fast(w1 * y[4] + w2 * c4);

    // ---- iteration 3: only position 0 ----
    float d0 = (z1 + z3 + z4) * i3;
    out[base + t] = sigmoid_fast(w1 * z0 + w2 * d0);
}

extern "C" void kernel_launch(void* const* d_in, const int* in_sizes, int n_in,
                              void* d_out, int out_size, void* d_ws, size_t ws_size,
                              hipStream_t stream) {
    const float* x   = (const float*)d_in[0];
    const float* w1p = (const float*)d_in[1];
    float* out = (float*)d_out;
    const int n = in_sizes[0] / 9;           // 4,000,000 patches
    const int blocks = (n + PPB - 1) / PPB;  // 15625 (exact: 4M % 256 == 0)
    dcn_56925496541545_kernel<<<blocks, PPB, 0, stream>>>(x, w1p, out, n);
}